// Round 10
// baseline (499.815 us; speedup 1.0000x reference)
//
#include <hip/hip_runtime.h>
#include <hip/hip_bf16.h>
#include <stdint.h>

typedef unsigned short u16;
typedef _Float16 f16;
typedef __attribute__((ext_vector_type(8))) f16 f16x8;
typedef __attribute__((ext_vector_type(4))) float f32x4;
typedef __attribute__((ext_vector_type(8))) u16 u16x8;

__device__ __forceinline__ u16 f2h(float f) {
    return __builtin_bit_cast(u16, (f16)f);
}
__device__ __forceinline__ float h2f(u16 u) {
    return (float)__builtin_bit_cast(f16, u);
}

#define GLDS16(g, l) __builtin_amdgcn_global_load_lds( \
    (const __attribute__((address_space(1))) void*)(uintptr_t)(g), \
    (__attribute__((address_space(3))) void*)(uintptr_t)(l), 16, 0, 0)

// ---------------- weight prep ----------------
__global__ __launch_bounds__(256) void transpose_w(
    const float* __restrict__ in, u16* __restrict__ out,
    int K, int N, int rowOff)
{
    __shared__ float tile[32][33];
    int n0 = blockIdx.x * 32;
    int k0 = blockIdx.y * 32;
    int tx = threadIdx.x & 31;
    int ty = threadIdx.x >> 5;
#pragma unroll
    for (int i = 0; i < 4; ++i) {
        int k = ty + i * 8;
        tile[k][tx] = in[(size_t)(k0 + k) * N + n0 + tx];
    }
    __syncthreads();
#pragma unroll
    for (int i = 0; i < 4; ++i) {
        int n = ty + i * 8;
        out[(size_t)(rowOff + n0 + n) * K + k0 + tx] = f2h(tile[tx][n]);
    }
}

__global__ __launch_bounds__(256) void transpose_w4(
    const float* __restrict__ wq, const float* __restrict__ wk,
    const float* __restrict__ wv, const float* __restrict__ wo,
    u16* __restrict__ wqkvT, u16* __restrict__ woT)
{
    __shared__ float tile[32][33];
    const float* src[4] = {wq, wk, wv, wo};
    const int z = blockIdx.z;
    const float* in = src[z];
    u16* out = (z == 3) ? woT : (wqkvT + (size_t)z * 512 * 512);
    int n0 = blockIdx.x * 32;
    int k0 = blockIdx.y * 32;
    int tx = threadIdx.x & 31;
    int ty = threadIdx.x >> 5;
#pragma unroll
    for (int i = 0; i < 4; ++i) {
        int k = ty + i * 8;
        tile[k][tx] = in[(size_t)(k0 + k) * 512 + n0 + tx];
    }
    __syncthreads();
#pragma unroll
    for (int i = 0; i < 4; ++i) {
        int n = ty + i * 8;
        out[(size_t)(n0 + n) * 512 + k0 + tx] = f2h(tile[tx][n]);
    }
}

// ---------------- QKV GEMM with fp32 A (x) staged in LDS --------------------
// C[M][1536] = x[M][512] @ wqkvT^T + bias(q|k|v). 128x128 tile, BK=64,
// 4 waves. A staged as fp32 (32 KB), converted to f16 at fragment read.
// T2 swizzle both paths; bijective XCD chunking on 1-D n-fastest grid.
__global__ __launch_bounds__(256, 2) void gemm_qkv(
    const float* __restrict__ X,
    const u16* __restrict__ BT,
    const float* __restrict__ bq, const float* __restrict__ bk,
    const float* __restrict__ bv,
    u16* __restrict__ outh, int nb_n, int N)
{
    __shared__ float Af[128 * 64];   // 32 KB fp32 A
    __shared__ u16   Bs[128 * 64];   // 16 KB f16 B
    const int tid  = threadIdx.x;
    const int lane = tid & 63;
    const int wv   = tid >> 6;
    const int nwg  = gridDim.x;
    const int cpx  = nwg >> 3;
    const int logical = (blockIdx.x & 7) * cpx + (blockIdx.x >> 3);
    const int m0   = (logical / nb_n) * 128;
    const int n0   = (logical % nb_n) * 128;
    const int wm   = (wv >> 1) * 64;
    const int wn   = (wv & 1) * 64;
    const int lhi  = lane >> 4;
    const int llo  = lane & 15;

    f32x4 acc[4][4] = {};

    for (int kt = 0; kt < 512; kt += 64) {
        __syncthreads();
        // stage A fp32: 128 rows x 64 floats = 2048 16B-chunks, 8/thread
#pragma unroll
        for (int i = 0; i < 8; ++i) {
            int c = i * 256 + tid;
            int row = c >> 4;                    // 16 chunks per 256-B row
            int sl = (c & 15) ^ (row & 7);       // inverse-swizzled source slot
            const float* ga = X + (size_t)(m0 + row) * 512 + kt + sl * 4;
            char* la = (char*)Af + ((i * 256 + wv * 64) << 4);
            GLDS16(ga, la);
        }
        // stage B f16: 1024 chunks, 4/thread (r5 path)
#pragma unroll
        for (int i = 0; i < 4; ++i) {
            int c = i * 256 + tid;
            int row = c >> 3;
            int chunk = (c & 7) ^ (row & 7);
            const u16* gb = BT + (size_t)(n0 + row) * 512 + kt + chunk * 8;
            char* lb = (char*)Bs + ((i * 256 + wv * 64) << 4);
            GLDS16(gb, lb);
        }
        __syncthreads();
#pragma unroll
        for (int fk = 0; fk < 2; ++fk) {
            f16x8 af[4], bfr[4];
#pragma unroll
            for (int f = 0; f < 4; ++f) {
                int ra = wm + f * 16 + llo;
                int bo = fk * 128 + lhi * 32;    // byte offset in 256-B row
                int sxa = (ra & 7) << 4;
                f32x4 a0 = *(const f32x4*)((const char*)Af +
                            ((ra << 8) + (bo ^ sxa)));
                f32x4 a1 = *(const f32x4*)((const char*)Af +
                            ((ra << 8) + ((bo + 16) ^ sxa)));
#pragma unroll
                for (int j = 0; j < 4; ++j) {
                    af[f][j]     = (f16)a0[j];
                    af[f][j + 4] = (f16)a1[j];
                }
                int rb = wn + f * 16 + llo;
                bfr[f] = *(const f16x8*)((const char*)Bs +
                        ((rb << 7) + ((fk * 64 + (lhi << 4)) ^ ((rb & 7) << 4))));
            }
#pragma unroll
            for (int fm = 0; fm < 4; ++fm)
#pragma unroll
                for (int fn = 0; fn < 4; ++fn)
                    acc[fm][fn] = __builtin_amdgcn_mfma_f32_16x16x32_f16(
                        af[fm], bfr[fn], acc[fm][fn], 0, 0, 0);
        }
    }

    // bias select (wave-uniform per block: 128-col tile lies in one segment)
    const float* bptr; int cbase;
    if (n0 < 512)       { bptr = bq; cbase = 0; }
    else if (n0 < 1024) { bptr = bk; cbase = 512; }
    else                { bptr = bv; cbase = 1024; }

    const int cr = lhi * 4;
#pragma unroll
    for (int fm = 0; fm < 4; ++fm) {
#pragma unroll
        for (int fn = 0; fn < 4; ++fn) {
            const int col = n0 + wn + fn * 16 + llo;
            const float bia = bptr[col - cbase];
#pragma unroll
            for (int r = 0; r < 4; ++r) {
                const int row = m0 + wm + fm * 16 + cr + r;
                outh[(size_t)row * N + col] = f2h(acc[fm][fn][r] + bia);
            }
        }
    }
}

// ---------------- GEMM: C = A[M][lda] * BT[N][ldb]^T (r5 exact) -------------
// RES: 0 none, 1 = fp32 residual, 2 = f16 residual.
template<int RES, bool RELU, bool WH, bool WF32>
__global__ __launch_bounds__(256, 2) void gemm_bt(
    const u16* __restrict__ A, int lda,
    const u16* __restrict__ BT, int ldb,
    const float* __restrict__ bias, const void* __restrict__ res,
    u16* __restrict__ outh, float* __restrict__ outf,
    int nb_n, int N, int K)
{
    __shared__ u16 As[128 * 64];
    __shared__ u16 Bs[128 * 64];
    const int tid  = threadIdx.x;
    const int lane = tid & 63;
    const int wv   = tid >> 6;
    const int nwg  = gridDim.x;
    const int cpx  = nwg >> 3;
    const int logical = (blockIdx.x & 7) * cpx + (blockIdx.x >> 3);
    const int m0   = (logical / nb_n) * 128;
    const int n0   = (logical % nb_n) * 128;
    const int wm   = (wv >> 1) * 64;
    const int wn   = (wv & 1) * 64;
    const int lhi  = lane >> 4;
    const int llo  = lane & 15;

    f32x4 acc[4][4] = {};

    for (int kt = 0; kt < K; kt += 64) {
        __syncthreads();
#pragma unroll
        for (int i = 0; i < 4; ++i) {
            int c = i * 256 + tid;
            int row = c >> 3;
            int chunk = (c & 7) ^ (row & 7);
            const u16* ga = A  + (size_t)(m0 + row) * lda + kt + chunk * 8;
            const u16* gb = BT + (size_t)(n0 + row) * ldb + kt + chunk * 8;
            char* la = (char*)As + ((i * 256 + wv * 64) << 4);
            char* lb = (char*)Bs + ((i * 256 + wv * 64) << 4);
            GLDS16(ga, la);
            GLDS16(gb, lb);
        }
        __syncthreads();
#pragma unroll
        for (int fk = 0; fk < 2; ++fk) {
            f16x8 af[4], bfr[4];
#pragma unroll
            for (int f = 0; f < 4; ++f) {
                int ra = wm + f * 16 + llo;
                af[f] = *(const f16x8*)((const char*)As +
                        ((ra << 7) + ((fk * 64 + (lhi << 4)) ^ ((ra & 7) << 4))));
                int rb = wn + f * 16 + llo;
                bfr[f] = *(const f16x8*)((const char*)Bs +
                        ((rb << 7) + ((fk * 64 + (lhi << 4)) ^ ((rb & 7) << 4))));
            }
#pragma unroll
            for (int fm = 0; fm < 4; ++fm)
#pragma unroll
                for (int fn = 0; fn < 4; ++fn)
                    acc[fm][fn] = __builtin_amdgcn_mfma_f32_16x16x32_f16(
                        af[fm], bfr[fn], acc[fm][fn], 0, 0, 0);
        }
    }

    const int cr = lhi * 4;
#pragma unroll
    for (int fm = 0; fm < 4; ++fm) {
#pragma unroll
        for (int fn = 0; fn < 4; ++fn) {
            const int col = n0 + wn + fn * 16 + llo;
            const float bia = bias[col];
#pragma unroll
            for (int r = 0; r < 4; ++r) {
                const int row = m0 + wm + fm * 16 + cr + r;
                float v = acc[fm][fn][r] + bia;
                if constexpr (RES == 1) v += ((const float*)res)[(size_t)row * N + col];
                if constexpr (RES == 2) v += h2f(((const u16*)res)[(size_t)row * N + col]);
                if constexpr (RELU) v = fmaxf(v, 0.f);
                if constexpr (WF32) outf[(size_t)row * N + col] = v;
                if constexpr (WH)   outh[(size_t)row * N + col] = f2h(v);
            }
        }
    }
}

// ---------------- fused attention, one block per (batch, head) --------------
__global__ __launch_bounds__(256, 2) void attn_kernel(
    const u16* __restrict__ qkv, u16* __restrict__ attn)
{
    __shared__ u16 VT[128 * 128];
    __shared__ u16 Plds[4 * 32 * 128];
    const int tid  = threadIdx.x;
    const int lane = tid & 63;
    const int wv   = tid >> 6;
    const int b    = blockIdx.x >> 2;
    const int hh   = blockIdx.x & 3;
    const int lhi  = lane >> 4;
    const int llo  = lane & 15;
    const u16* base = qkv + (size_t)b * 128 * 1536;

#pragma unroll
    for (int i = 0; i < 8; ++i) {
        int c = i * 256 + tid;
        int t = c >> 4;
        int ch = c & 15;
        uint4 raw = *(const uint4*)(base + (size_t)t * 1536 + 1024 + hh * 128 + ch * 8);
        const u16* e = (const u16*)&raw;
#pragma unroll
        for (int j = 0; j < 8; ++j) {
            int d = ch * 8 + j;
            *(u16*)((char*)VT + ((d << 8) + ((t * 2) ^ ((d & 7) << 4)))) = e[j];
        }
    }

    f16x8 qf[2][4];
#pragma unroll
    for (int fm = 0; fm < 2; ++fm)
#pragma unroll
        for (int fk = 0; fk < 4; ++fk) {
            int srow = wv * 32 + fm * 16 + llo;
            qf[fm][fk] = *(const f16x8*)(base + (size_t)srow * 1536 + hh * 128 + fk * 32 + lhi * 8);
        }

    f32x4 acc[2][8] = {};
#pragma unroll
    for (int ft = 0; ft < 8; ++ft) {
        f16x8 kf[4];
#pragma unroll
        for (int fk = 0; fk < 4; ++fk) {
            int trow = ft * 16 + llo;
            kf[fk] = *(const f16x8*)(base + (size_t)trow * 1536 + 512 + hh * 128 + fk * 32 + lhi * 8);
        }
#pragma unroll
        for (int fm = 0; fm < 2; ++fm)
#pragma unroll
            for (int fk = 0; fk < 4; ++fk)
                acc[fm][ft] = __builtin_amdgcn_mfma_f32_16x16x32_f16(
                    qf[fm][fk], kf[fk], acc[fm][ft], 0, 0, 0);
    }

    float inv[2][4];
#pragma unroll
    for (int fm = 0; fm < 2; ++fm)
#pragma unroll
        for (int r = 0; r < 4; ++r) {
            float mx = acc[fm][0][r];
#pragma unroll
            for (int ft = 1; ft < 8; ++ft) mx = fmaxf(mx, acc[fm][ft][r]);
            mx = fmaxf(mx, __shfl_xor(mx, 1, 64));
            mx = fmaxf(mx, __shfl_xor(mx, 2, 64));
            mx = fmaxf(mx, __shfl_xor(mx, 4, 64));
            mx = fmaxf(mx, __shfl_xor(mx, 8, 64));
            float s = 0.f;
#pragma unroll
            for (int ft = 0; ft < 8; ++ft) {
                float p = __expf(acc[fm][ft][r] - mx);
                acc[fm][ft][r] = p;
                s += p;
            }
            s += __shfl_xor(s, 1, 64);
            s += __shfl_xor(s, 2, 64);
            s += __shfl_xor(s, 4, 64);
            s += __shfl_xor(s, 8, 64);
            inv[fm][r] = 1.f / s;
        }

    char* Pw = (char*)Plds + wv * 8192;
#pragma unroll
    for (int fm = 0; fm < 2; ++fm)
#pragma unroll
        for (int ft = 0; ft < 8; ++ft)
#pragma unroll
            for (int r = 0; r < 4; ++r) {
                int m = fm * 16 + lhi * 4 + r;
                int t = ft * 16 + llo;
                *(u16*)(Pw + ((m << 8) + ((t * 2) ^ ((m & 7) << 4)))) = f2h(acc[fm][ft][r]);
            }

    __syncthreads();

    f16x8 pf[2][4];
#pragma unroll
    for (int fm = 0; fm < 2; ++fm)
#pragma unroll
        for (int k2 = 0; k2 < 4; ++k2) {
            int m = fm * 16 + llo;
            pf[fm][k2] = *(const f16x8*)(Pw +
                ((m << 8) + ((k2 * 64 + (lhi << 4)) ^ ((m & 7) << 4))));
        }

    f32x4 o[2][8] = {};
#pragma unroll
    for (int fd = 0; fd < 8; ++fd) {
        f16x8 vf[4];
#pragma unroll
        for (int k2 = 0; k2 < 4; ++k2) {
            int d = fd * 16 + llo;
            vf[k2] = *(const f16x8*)((const char*)VT +
                ((d << 8) + ((k2 * 64 + (lhi << 4)) ^ ((d & 7) << 4))));
        }
#pragma unroll
        for (int fm = 0; fm < 2; ++fm)
#pragma unroll
            for (int k2 = 0; k2 < 4; ++k2)
                o[fm][fd] = __builtin_amdgcn_mfma_f32_16x16x32_f16(
                    pf[fm][k2], vf[k2], o[fm][fd], 0, 0, 0);
    }

#pragma unroll
    for (int fm = 0; fm < 2; ++fm)
#pragma unroll
        for (int fd = 0; fd < 8; ++fd)
#pragma unroll
            for (int r = 0; r < 4; ++r) {
                int row = b * 128 + wv * 32 + fm * 16 + lhi * 4 + r;
                int col = hh * 128 + fd * 16 + llo;
                attn[(size_t)row * 512 + col] = f2h(o[fm][fd][r] * inv[fm][r]);
            }
}

// ---------------- launch -----------------------------------------------------
extern "C" void kernel_launch(void* const* d_in, const int* in_sizes, int n_in,
                              void* d_out, int out_size, void* d_ws, size_t ws_size,
                              hipStream_t stream)
{
    const float* x  = (const float*)d_in[0];
    const float* wq = (const float*)d_in[1];
    const float* bq = (const float*)d_in[2];
    const float* wk = (const float*)d_in[3];
    const float* bk = (const float*)d_in[4];
    const float* wv = (const float*)d_in[5];
    const float* bv = (const float*)d_in[6];
    const float* wo = (const float*)d_in[7];
    const float* bo = (const float*)d_in[8];
    const float* w1 = (const float*)d_in[9];
    const float* b1 = (const float*)d_in[10];
    const float* w2 = (const float*)d_in[11];
    const float* b2 = (const float*)d_in[12];
    float* out = (float*)d_out;

    char* ws = (char*)d_ws;
    u16*   wqkvT = (u16*)(ws + 0);                 // [1536][512] f16  1,572,864
    u16*   woT   = (u16*)(ws + 1572864);           // [512][512]         524,288
    u16*   w1T   = (u16*)(ws + 2097152);           // [2048][512]      2,097,152
    u16*   w2T   = (u16*)(ws + 4194304);           // [512][2048]      2,097,152
    u16*   x1h   = (u16*)(ws + 6297600);           // [M][512]  50,331,648
    u16*   qkv   = (u16*)(ws + 56629248);          // [M][1536] 150,994,944
    u16*   attno = (u16*)(ws + 207624192);         // [M][512]   50,331,648 -> 257,955,840
    u16*   hbuf  = qkv;                            // [M][2048] over dead qkv+attno

    // ---- prep (3 dispatches) ----
    transpose_w4<<<dim3(16, 16, 4), 256, 0, stream>>>(wq, wk, wv, wo, wqkvT, woT);
    transpose_w<<<dim3(64, 16), 256, 0, stream>>>(w1, w1T, 512, 2048, 0);
    transpose_w<<<dim3(16, 64), 256, 0, stream>>>(w2, w2T, 2048, 512, 0);

    // ---- qkv = x @ [wq|wk|wv] + b  (fp32 A staged, converted in-kernel) ----
    gemm_qkv<<<4608, 256, 0, stream>>>(
        x, wqkvT, bq, bk, bv, qkv, 12, 1536);
    // ---- attention -> attno ----
    attn_kernel<<<1536, 256, 0, stream>>>(qkv, attno);
    // ---- x1 = x(fp32) + attn @ wo + bo  (f16 -> x1h) ----
    gemm_bt<1, false, true, false><<<1536, 256, 0, stream>>>(
        attno, 512, woT, 512, bo, x, x1h, nullptr, 4, 512, 512);
    // ---- h = relu(x1 @ w1 + b1) ----
    gemm_bt<0, true, true, false><<<6144, 256, 0, stream>>>(
        x1h, 512, w1T, 512, b1, nullptr, hbuf, nullptr, 16, 2048, 512);
    // ---- out = x1 + h @ w2 + b2  (fp32 to d_out) ----
    gemm_bt<2, false, false, true><<<1536, 256, 0, stream>>>(
        hbuf, 2048, w2T, 2048, b2, x1h, nullptr, out, 4, 512, 2048);
}

// Round 11
// 425.972 us; speedup vs baseline: 1.1734x; 1.1734x over previous
//
#include <hip/hip_runtime.h>
#include <hip/hip_bf16.h>
#include <stdint.h>

typedef unsigned short u16;
typedef _Float16 f16;
typedef __attribute__((ext_vector_type(8))) f16 f16x8;
typedef __attribute__((ext_vector_type(4))) float f32x4;
typedef __attribute__((ext_vector_type(8))) u16 u16x8;

__device__ __forceinline__ u16 f2h(float f) {
    return __builtin_bit_cast(u16, (f16)f);
}
__device__ __forceinline__ float h2f(u16 u) {
    return (float)__builtin_bit_cast(f16, u);
}

#define GLDS16(g, l) __builtin_amdgcn_global_load_lds( \
    (const __attribute__((address_space(1))) void*)(uintptr_t)(g), \
    (__attribute__((address_space(3))) void*)(uintptr_t)(l), 16, 0, 0)

// ---------------- fused prep: all weight transposes + bias pack + x->f16 ----
// Block ranges:
//   [0, 12288)       convert_x   (12288 blocks, 8 f32->f16 per thread)
//   [12288, 13312)   4x 512x512 transposes (wq,wk,wv -> wqkvT; wo -> woT)
//   [13312, 14336)   w1 [512][2048] -> w1T [2048][512]
//   [14336, 15360)   w2 [2048][512] -> w2T [512][2048]
//   [15360, 15366)   bias pack bq|bk|bv -> bqkv
__global__ __launch_bounds__(256) void prep_all(
    const float* __restrict__ x,
    const float* __restrict__ wq, const float* __restrict__ wk,
    const float* __restrict__ wv, const float* __restrict__ wo,
    const float* __restrict__ w1, const float* __restrict__ w2,
    const float* __restrict__ bq, const float* __restrict__ bk,
    const float* __restrict__ bv,
    u16* __restrict__ xf, u16* __restrict__ wqkvT, u16* __restrict__ woT,
    u16* __restrict__ w1T, u16* __restrict__ w2T, float* __restrict__ bqkv)
{
    __shared__ float tile[32][33];
    const int bid = blockIdx.x;

    if (bid < 12288) {                       // ---- x fp32 -> f16 ----
        size_t i = ((size_t)bid * 256 + threadIdx.x) * 8;
        float4 a = *(const float4*)(x + i);
        float4 b = *(const float4*)(x + i + 4);
        u16x8 r;
        r[0] = f2h(a.x); r[1] = f2h(a.y); r[2] = f2h(a.z); r[3] = f2h(a.w);
        r[4] = f2h(b.x); r[5] = f2h(b.y); r[6] = f2h(b.z); r[7] = f2h(b.w);
        *(u16x8*)(xf + i) = r;
        return;
    }
    if (bid >= 15360) {                      // ---- bias pack (6 blocks) ----
        int i = (bid - 15360) * 256 + threadIdx.x;
        float v;
        if (i < 512) v = bq[i];
        else if (i < 1024) v = bk[i - 512];
        else v = bv[i - 1024];
        bqkv[i] = v;
        return;
    }

    // ---- transposes: decode source/dest/geometry ----
    const float* in; u16* outp; int N, K, n0, k0;
    if (bid < 13312) {                       // 4x 512^2
        int local = bid - 12288;
        int z = local >> 8;
        const float* src[4] = {wq, wk, wv, wo};
        in = src[z];
        outp = (z == 3) ? woT : (wqkvT + (size_t)z * 512 * 512);
        int rem = local & 255;
        n0 = (rem & 15) * 32; k0 = (rem >> 4) * 32;
        N = 512; K = 512;
    } else if (bid < 14336) {                // w1: K=512, N=2048
        int local = bid - 13312;
        in = w1; outp = w1T;
        n0 = (local & 63) * 32; k0 = (local >> 6) * 32;
        N = 2048; K = 512;
    } else {                                 // w2: K=2048, N=512
        int local = bid - 14336;
        in = w2; outp = w2T;
        n0 = (local & 15) * 32; k0 = (local >> 4) * 32;
        N = 512; K = 2048;
    }
    const int tx = threadIdx.x & 31;
    const int ty = threadIdx.x >> 5;
#pragma unroll
    for (int i = 0; i < 4; ++i) {
        int k = ty + i * 8;
        tile[k][tx] = in[(size_t)(k0 + k) * N + n0 + tx];
    }
    __syncthreads();
#pragma unroll
    for (int i = 0; i < 4; ++i) {
        int n = ty + i * 8;
        outp[(size_t)(n0 + n) * K + k0 + tx] = f2h(tile[tx][n]);
    }
}

// ---------------- GEMM: C = A[M][lda] * BT[N][ldb]^T (r5 exact) -------------
// 128x128 tile, BK=64, 4 waves, global_load_lds w16, T2 swizzle via
// pre-swizzled global source, 1-D grid n-fastest + bijective XCD chunking.
// RES: 0 none, 2 = f16 residual.
template<int RES, bool RELU, bool WH, bool WF32>
__global__ __launch_bounds__(256, 2) void gemm_bt(
    const u16* __restrict__ A, int lda,
    const u16* __restrict__ BT, int ldb,
    const float* __restrict__ bias, const void* __restrict__ res,
    u16* __restrict__ outh, float* __restrict__ outf,
    int nb_n, int N, int K)
{
    __shared__ u16 As[128 * 64];
    __shared__ u16 Bs[128 * 64];
    const int tid  = threadIdx.x;
    const int lane = tid & 63;
    const int wv   = tid >> 6;
    const int nwg  = gridDim.x;
    const int cpx  = nwg >> 3;
    const int logical = (blockIdx.x & 7) * cpx + (blockIdx.x >> 3);
    const int m0   = (logical / nb_n) * 128;
    const int n0   = (logical % nb_n) * 128;
    const int wm   = (wv >> 1) * 64;
    const int wn   = (wv & 1) * 64;
    const int lhi  = lane >> 4;
    const int llo  = lane & 15;

    f32x4 acc[4][4] = {};

    for (int kt = 0; kt < K; kt += 64) {
        __syncthreads();
#pragma unroll
        for (int i = 0; i < 4; ++i) {
            int c = i * 256 + tid;
            int row = c >> 3;
            int chunk = (c & 7) ^ (row & 7);
            const u16* ga = A  + (size_t)(m0 + row) * lda + kt + chunk * 8;
            const u16* gb = BT + (size_t)(n0 + row) * ldb + kt + chunk * 8;
            char* la = (char*)As + ((i * 256 + wv * 64) << 4);
            char* lb = (char*)Bs + ((i * 256 + wv * 64) << 4);
            GLDS16(ga, la);
            GLDS16(gb, lb);
        }
        __syncthreads();
#pragma unroll
        for (int fk = 0; fk < 2; ++fk) {
            f16x8 af[4], bfr[4];
#pragma unroll
            for (int f = 0; f < 4; ++f) {
                int ra = wm + f * 16 + llo;
                af[f] = *(const f16x8*)((const char*)As +
                        ((ra << 7) + ((fk * 64 + (lhi << 4)) ^ ((ra & 7) << 4))));
                int rb = wn + f * 16 + llo;
                bfr[f] = *(const f16x8*)((const char*)Bs +
                        ((rb << 7) + ((fk * 64 + (lhi << 4)) ^ ((rb & 7) << 4))));
            }
#pragma unroll
            for (int fm = 0; fm < 4; ++fm)
#pragma unroll
                for (int fn = 0; fn < 4; ++fn)
                    acc[fm][fn] = __builtin_amdgcn_mfma_f32_16x16x32_f16(
                        af[fm], bfr[fn], acc[fm][fn], 0, 0, 0);
        }
    }

    const int cr = lhi * 4;
#pragma unroll
    for (int fm = 0; fm < 4; ++fm) {
#pragma unroll
        for (int fn = 0; fn < 4; ++fn) {
            const int col = n0 + wn + fn * 16 + llo;
            const float bia = bias[col];
#pragma unroll
            for (int r = 0; r < 4; ++r) {
                const int row = m0 + wm + fm * 16 + cr + r;
                float v = acc[fm][fn][r] + bia;
                if constexpr (RES == 2) v += h2f(((const u16*)res)[(size_t)row * N + col]);
                if constexpr (RELU) v = fmaxf(v, 0.f);
                if constexpr (WF32) outf[(size_t)row * N + col] = v;
                if constexpr (WH)   outh[(size_t)row * N + col] = f2h(v);
            }
        }
    }
}

// ---------------- fused attention, one block per (batch, head) --------------
__global__ __launch_bounds__(256, 2) void attn_kernel(
    const u16* __restrict__ qkv, u16* __restrict__ attn)
{
    __shared__ u16 VT[128 * 128];
    __shared__ u16 Plds[4 * 32 * 128];
    const int tid  = threadIdx.x;
    const int lane = tid & 63;
    const int wv   = tid >> 6;
    const int b    = blockIdx.x >> 2;
    const int hh   = blockIdx.x & 3;
    const int lhi  = lane >> 4;
    const int llo  = lane & 15;
    const u16* base = qkv + (size_t)b * 128 * 1536;

#pragma unroll
    for (int i = 0; i < 8; ++i) {
        int c = i * 256 + tid;
        int t = c >> 4;
        int ch = c & 15;
        uint4 raw = *(const uint4*)(base + (size_t)t * 1536 + 1024 + hh * 128 + ch * 8);
        const u16* e = (const u16*)&raw;
#pragma unroll
        for (int j = 0; j < 8; ++j) {
            int d = ch * 8 + j;
            *(u16*)((char*)VT + ((d << 8) + ((t * 2) ^ ((d & 7) << 4)))) = e[j];
        }
    }

    f16x8 qf[2][4];
#pragma unroll
    for (int fm = 0; fm < 2; ++fm)
#pragma unroll
        for (int fk = 0; fk < 4; ++fk) {
            int srow = wv * 32 + fm * 16 + llo;
            qf[fm][fk] = *(const f16x8*)(base + (size_t)srow * 1536 + hh * 128 + fk * 32 + lhi * 8);
        }

    f32x4 acc[2][8] = {};
#pragma unroll
    for (int ft = 0; ft < 8; ++ft) {
        f16x8 kf[4];
#pragma unroll
        for (int fk = 0; fk < 4; ++fk) {
            int trow = ft * 16 + llo;
            kf[fk] = *(const f16x8*)(base + (size_t)trow * 1536 + 512 + hh * 128 + fk * 32 + lhi * 8);
        }
#pragma unroll
        for (int fm = 0; fm < 2; ++fm)
#pragma unroll
            for (int fk = 0; fk < 4; ++fk)
                acc[fm][ft] = __builtin_amdgcn_mfma_f32_16x16x32_f16(
                    qf[fm][fk], kf[fk], acc[fm][ft], 0, 0, 0);
    }

    float inv[2][4];
#pragma unroll
    for (int fm = 0; fm < 2; ++fm)
#pragma unroll
        for (int r = 0; r < 4; ++r) {
            float mx = acc[fm][0][r];
#pragma unroll
            for (int ft = 1; ft < 8; ++ft) mx = fmaxf(mx, acc[fm][ft][r]);
            mx = fmaxf(mx, __shfl_xor(mx, 1, 64));
            mx = fmaxf(mx, __shfl_xor(mx, 2, 64));
            mx = fmaxf(mx, __shfl_xor(mx, 4, 64));
            mx = fmaxf(mx, __shfl_xor(mx, 8, 64));
            float s = 0.f;
#pragma unroll
            for (int ft = 0; ft < 8; ++ft) {
                float p = __expf(acc[fm][ft][r] - mx);
                acc[fm][ft][r] = p;
                s += p;
            }
            s += __shfl_xor(s, 1, 64);
            s += __shfl_xor(s, 2, 64);
            s += __shfl_xor(s, 4, 64);
            s += __shfl_xor(s, 8, 64);
            inv[fm][r] = 1.f / s;
        }

    char* Pw = (char*)Plds + wv * 8192;
#pragma unroll
    for (int fm = 0; fm < 2; ++fm)
#pragma unroll
        for (int ft = 0; ft < 8; ++ft)
#pragma unroll
            for (int r = 0; r < 4; ++r) {
                int m = fm * 16 + lhi * 4 + r;
                int t = ft * 16 + llo;
                *(u16*)(Pw + ((m << 8) + ((t * 2) ^ ((m & 7) << 4)))) = f2h(acc[fm][ft][r]);
            }

    __syncthreads();

    f16x8 pf[2][4];
#pragma unroll
    for (int fm = 0; fm < 2; ++fm)
#pragma unroll
        for (int k2 = 0; k2 < 4; ++k2) {
            int m = fm * 16 + llo;
            pf[fm][k2] = *(const f16x8*)(Pw +
                ((m << 8) + ((k2 * 64 + (lhi << 4)) ^ ((m & 7) << 4))));
        }

    f32x4 o[2][8] = {};
#pragma unroll
    for (int fd = 0; fd < 8; ++fd) {
        f16x8 vf[4];
#pragma unroll
        for (int k2 = 0; k2 < 4; ++k2) {
            int d = fd * 16 + llo;
            vf[k2] = *(const f16x8*)((const char*)VT +
                ((d << 8) + ((k2 * 64 + (lhi << 4)) ^ ((d & 7) << 4))));
        }
#pragma unroll
        for (int fm = 0; fm < 2; ++fm)
#pragma unroll
            for (int k2 = 0; k2 < 4; ++k2)
                o[fm][fd] = __builtin_amdgcn_mfma_f32_16x16x32_f16(
                    pf[fm][k2], vf[k2], o[fm][fd], 0, 0, 0);
    }

#pragma unroll
    for (int fm = 0; fm < 2; ++fm)
#pragma unroll
        for (int fd = 0; fd < 8; ++fd)
#pragma unroll
            for (int r = 0; r < 4; ++r) {
                int row = b * 128 + wv * 32 + fm * 16 + lhi * 4 + r;
                int col = hh * 128 + fd * 16 + llo;
                attn[(size_t)row * 512 + col] = f2h(o[fm][fd][r] * inv[fm][r]);
            }
}

// ---------------- launch -----------------------------------------------------
extern "C" void kernel_launch(void* const* d_in, const int* in_sizes, int n_in,
                              void* d_out, int out_size, void* d_ws, size_t ws_size,
                              hipStream_t stream)
{
    const float* x  = (const float*)d_in[0];
    const float* wq = (const float*)d_in[1];
    const float* bq = (const float*)d_in[2];
    const float* wk = (const float*)d_in[3];
    const float* bk = (const float*)d_in[4];
    const float* wv = (const float*)d_in[5];
    const float* bv = (const float*)d_in[6];
    const float* wo = (const float*)d_in[7];
    const float* bo = (const float*)d_in[8];
    const float* w1 = (const float*)d_in[9];
    const float* b1 = (const float*)d_in[10];
    const float* w2 = (const float*)d_in[11];
    const float* b2 = (const float*)d_in[12];
    float* out = (float*)d_out;

    char* ws = (char*)d_ws;
    u16*   wqkvT = (u16*)(ws + 0);                 // [1536][512] f16  1,572,864
    u16*   woT   = (u16*)(ws + 1572864);           // [512][512]         524,288
    u16*   w1T   = (u16*)(ws + 2097152);           // [2048][512]      2,097,152
    u16*   w2T   = (u16*)(ws + 4194304);           // [512][2048]      2,097,152
    float* bqkv  = (float*)(ws + 6291456);         // [1536]               6,144
    u16*   xf    = (u16*)(ws + 6297600);           // [M][512]  50,331,648
    u16*   qkv   = (u16*)(ws + 56629248);          // [M][1536] 150,994,944
    u16*   attno = (u16*)(ws + 207624192);         // [M][512]   50,331,648 -> 257,955,840
    u16*   x1h   = xf;                             // in-place over xf (same-elem r/w)
    u16*   hbuf  = qkv;                            // [M][2048] over dead qkv+attno

    // ---- fused prep (1 dispatch) ----
    prep_all<<<15366, 256, 0, stream>>>(
        x, wq, wk, wv, wo, w1, w2, bq, bk, bv,
        xf, wqkvT, woT, w1T, w2T, bqkv);

    // ---- qkv = x @ [wq|wk|wv] + b ----
    gemm_bt<0, false, true, false><<<4608, 256, 0, stream>>>(
        xf, 512, wqkvT, 512, bqkv, nullptr, qkv, nullptr, 12, 1536, 512);
    // ---- attention -> attno ----
    attn_kernel<<<1536, 256, 0, stream>>>(qkv, attno);
    // ---- x1 = xf + attn @ wo + bo  (f16, in-place over xf) ----
    gemm_bt<2, false, true, false><<<1536, 256, 0, stream>>>(
        attno, 512, woT, 512, bo, xf, x1h, nullptr, 4, 512, 512);
    // ---- h = relu(x1 @ w1 + b1) ----
    gemm_bt<0, true, true, false><<<6144, 256, 0, stream>>>(
        x1h, 512, w1T, 512, b1, nullptr, hbuf, nullptr, 16, 2048, 512);
    // ---- out = x1 + h @ w2 + b2  (fp32 to d_out) ----
    gemm_bt<2, false, false, true><<<1536, 256, 0, stream>>>(
        hbuf, 2048, w2T, 2048, b2, x1h, nullptr, out, 4, 512, 2048);
}